// Round 4
// baseline (128.384 us; speedup 1.0000x reference)
//
#include <hip/hip_runtime.h>

// out[128,16384] = [A|B](128x8384) @ [x; x2](8384x16384), fp16 MFMA.
// Round 13 = round 12 + BN 128->256 (wt-vmem amortization).
// Evidence: r10 split-K x2->x4 left gemm time EXACTLY unchanged (pipe-bound,
// not latency); r12 halved VALU -> only -5%. Remaining accounting: per CU
// 528 wave-steps x 8KB af loads = 4.2 MB through the per-CU L1 return port
// (~66-131k cyc at 64-32 B/cyc) = the ~90% pipe. The 4 wn-waves re-load
// IDENTICAL wt fragments (4x redundancy) and every b0-block reads the same
// 2.1 MB wt stream (1.08 GB L2 total).
// Fix: BN=256 -> per-CU and total wt traffic halve. acc 4x4 (64 VGPR),
// ~2 waves/SIMD (fine: pipe-bound). xt = 256x128 fp16 = exactly 64 KB via
// octet-XOR swizzle idx = n*128 + (r ^ ((n&7)<<3)) (conflict-free: all
// reads/writes are octet-aligned b128 or scalar; swizzle spreads rows'
// octets across banks). ppc LDS table -> two prefetched pp dword reads/step.
// DO NOT add __launch_bounds__ min-waves: clamped VGPR -> spills (r6).
// K permutation: identity k'<128 (steps 0-1) | NICE [128,7936) (steps 2-123,
// uniform i, aligned j-octet) | RAGGED [7936,8384) (steps 124-130, gather).

constexpr int N_     = 128;
constexpr int S_     = 8256;
constexpr int BATCH_ = 16384;
constexpr int KTOT   = 8384;         // 131*64
constexpr int NKT    = 131;
constexpr size_t WT_BYTES = (size_t)KTOT * 128 * 2;
constexpr size_t PP_OFF   = WT_BYTES;

typedef __attribute__((ext_vector_type(8))) _Float16 half8;
typedef __attribute__((ext_vector_type(2))) _Float16 half2t;
typedef __attribute__((ext_vector_type(4))) float f32x4;

__device__ __forceinline__ ushort f2h(float f) {     // f32 -> fp16 bits (RNE)
    _Float16 h = (_Float16)f;
    ushort b; __builtin_memcpy(&b, &h, 2); return b;
}
__device__ __forceinline__ float h2f(ushort b) {
    _Float16 h; __builtin_memcpy(&h, &b, 2); return (float)h;
}
__device__ __forceinline__ half2t duph(ushort b) {   // {h, h} packed
    uint w = ((uint)b << 16) | (uint)b;
    half2t d; __builtin_memcpy(&d, &w, 4); return d;
}
__device__ __forceinline__ half8 mul_bc(half8 w, half2t d) {  // 4x v_pk_mul_f16
    union { half8 h; half2t p[4]; } u, r;
    u.h = w;
    #pragma unroll
    for (int q = 0; q < 4; ++q) r.p[q] = u.p[q] * d;
    return r.h;
}

// ---------- closed-form permutation helpers ----------
// cumN(i) = #NICE octets for rows < i = sum_{q<i} (16 - ceil(q/8))
__device__ __forceinline__ int cumN(int i) {
    if (i <= 0) return 0;
    const int n = i - 1, t = n >> 3, r = n & 7;
    return 16 * i - (4 * t * (t + 1) + r * (t + 1));
}
// offR(i) = #ragged entries for rows < i = sum_{q<i} ((8-(q&7))&7)
__device__ __forceinline__ int offR(int i) {
    const int a = i >> 3, b = i & 7;
    const int p = b ? (8 * (b - 1) - (((b - 1) * b) >> 1)) : 0;
    return 28 * a + p;
}
__device__ __forceinline__ int triS(int i) { return i * (257 - i) / 2; }

// ---------- fused build: zero out + pp table + wt (no internal deps) ----------
// W section (blocks [0,524)): thread (ko,m) -> 8 wt elems (one b128 store).
//   wt elem e = kt*8192 + kk*4096 + wm*2048 + mt*512 + lane*8 + el holds
//   W[m = wm*64+mt*16+(lane&15)][ perm(kt*64 + kk*32 + (lane>>4)*8 + el) ]
// Z section (blocks [524,780)): zero out[128,16384].
// P section (block 780): pp[k'] = i | (j<<8)  (j=0xFF marks A column i).
__global__ __launch_bounds__(256) void build_all(
    const float* __restrict__ A, const float* __restrict__ B,
    ushort* __restrict__ pp, ushort* __restrict__ wt,
    float* __restrict__ out)
{
    const int bid = blockIdx.x, t = threadIdx.x;
    if (bid < 524) {                              // ---- W: 1048 k-octets x 128 m ----
        const int idx = bid * 256 + t;            // [0, 134144)
        const int ko  = idx >> 7;                 // k-octet
        const int m   = idx & 127;
        const int kt = ko >> 3, kk = (ko >> 2) & 1, oct = ko & 3;
        const int lane = oct * 16 + (m & 15);
        const int e0 = kt * 8192 + kk * 4096 + (m >> 6) * 2048 +
                       ((m >> 4) & 3) * 512 + lane * 8;
        float v[8];
        if (ko < 16) {                            // identity: k = ko*8+el, A[m][k]
            const int i0 = ko * 8;
            #pragma unroll
            for (int el = 0; el < 8; ++el) v[el] = A[m * 128 + i0 + el];
        } else if (ko < 992) {                    // NICE: uniform i, aligned j-octet
            const int o = ko - 16;
            int i = 0;
            #pragma unroll
            for (int st = 64; st >= 1; st >>= 1) {
                const int c = i + st;
                if (c < 128 && cumN(c) <= o) i = c;
            }
            const int jb = ((i + 7) >> 3) + (o - cumN(i));
            const int s0 = triS(i) + jb * 8 - i;  // s = tri(i) + (j - i)
            const float* bp = B + (size_t)m * S_ + s0;
            #pragma unroll
            for (int el = 0; el < 8; ++el) v[el] = bp[el];
        } else {                                  // RAGGED: per-el gather
            const int kb = ko * 8 - 7936;
            #pragma unroll
            for (int el = 0; el < 8; ++el) {
                const int kloc = kb + el;
                int i = 0;
                #pragma unroll
                for (int st = 64; st >= 1; st >>= 1) {
                    const int c = i + st;
                    if (c < 128 && offR(c) <= kloc) i = c;
                }
                v[el] = B[(size_t)m * S_ + triS(i) + (kloc - offR(i))];
            }
        }
        ushort o8[8];
        #pragma unroll
        for (int el = 0; el < 8; ++el) o8[el] = f2h(v[el]);
        __builtin_memcpy(wt + e0, o8, 16);
    } else if (bid < 780) {                       // ---- Z: zero out ----
        const int zb = bid - 524;
        f32x4* o4 = (f32x4*)out;
        #pragma unroll
        for (int c = 0; c < 4; ++c)
            o4[(size_t)zb * 2048 + c * 512 + t] = (f32x4){0.f, 0.f, 0.f, 0.f};
    } else {                                      // ---- P: pp table ----
        const int i = t;
        if (i < 128) {
            pp[i] = (ushort)(i | (0xFFu << 8));
            const int jb0 = (i + 7) >> 3;
            int kb = 128 + cumN(i) * 8;
            for (int jb = jb0; jb < 16; ++jb) {
                #pragma unroll
                for (int e = 0; e < 8; ++e)
                    pp[kb + e] = (ushort)(i | ((jb * 8 + e) << 8));
                kb += 8;
            }
            const int h = (8 - (i & 7)) & 7;
            const int rb = 7936 + offR(i);
            for (int e = 0; e < h; ++e)
                pp[rb + e] = (ushort)(i | ((i + e) << 8));
        }
    }
}

// A-frags for step kt: 8 lane-linear b128 loads (coalesced layout).
__device__ __forceinline__ void load_af(half8 af[8], const ushort* __restrict__ wt,
                                        int kt, int wm, int lane) {
    const ushort* ab = wt + ((size_t)kt << 13) + (wm << 11) + (lane << 3);
    #pragma unroll
    for (int kk = 0; kk < 2; ++kk)
        #pragma unroll
        for (int mt = 0; mt < 4; ++mt)
            af[kk * 4 + mt] = *(const half8*)(ab + (kk << 12) + (mt << 9));
}

// NICE-step: gen B-frags for 4 n-tiles from pair words + MFMA.
// xbase = xt + (wn*64 + l16)*128; n-tile nt at byte offset nt*4096.
// Swizzled LDS index for row r of column n: r ^ ((n&7)<<3) = r ^ sw.
__device__ __forceinline__ void step_nice(f32x4 acc[4][4], const half8 af[8],
                                          uint w0, uint w1,
                                          const ushort* __restrict__ xbase,
                                          int sw) {
    const int ia = (int)(w0 & 0xFFu) ^ sw, ja = (int)((w0 >> 8) & 0xFFu) ^ sw;
    const int ib = (int)(w1 & 0xFFu) ^ sw, jb = (int)((w1 >> 8) & 0xFFu) ^ sw;
    ushort xi[2][4];
    half8  wj[2][4];
    #pragma unroll
    for (int nt = 0; nt < 4; ++nt) {
        const ushort* xb = xbase + nt * 2048;
        xi[0][nt] = xb[ia];
        xi[1][nt] = xb[ib];
        wj[0][nt] = *(const half8*)(xb + ja);
        wj[1][nt] = *(const half8*)(xb + jb);
    }
    #pragma unroll
    for (int kk = 0; kk < 2; ++kk)
        #pragma unroll
        for (int nt = 0; nt < 4; ++nt) {
            const half8 bfr = mul_bc(wj[kk][nt], duph(xi[kk][nt]));
            #pragma unroll
            for (int mt = 0; mt < 4; ++mt)
                acc[mt][nt] = __builtin_amdgcn_mfma_f32_16x16x32_f16(
                    af[kk * 4 + mt], bfr, acc[mt][nt], 0, 0, 0);
        }
}

// ---------- phase 2: fused MFMA GEMM, 128x256 tile, split-K x4 ----------
__global__ __launch_bounds__(512) void gemm_mfma(
    const float*  __restrict__ x,
    const ushort* __restrict__ wt,
    const ushort* __restrict__ pp,
    float* __restrict__ out)
{
    __shared__ ushort xt[256 * 128];   // exactly 64 KB, octet-XOR swizzled

    const int t    = threadIdx.x;
    const int b0   = blockIdx.x * 256;
    const int sp   = blockIdx.y;       // 0..3
    const int kt0  = sp * 33;          // 0,33,66,99
    const int kt1  = (sp == 3) ? NKT : kt0 + 33;
    const int lane = t & 63;
    const int w    = t >> 6;
    const int wm   = w >> 2, wn = w & 3;   // wave covers 64 m x 64 n
    const int l16  = lane & 15, quad = lane >> 4;
    const int sw   = (l16 & 7) << 3;

    // ---- stage xt: coalesced global reads, fp16, swizzled b128 LDS writes ----
    {
        const int n = t & 255, g = t >> 8;
        const int swn = (n & 7) << 3;
        #pragma unroll
        for (int c = 0; c < 8; ++c) {
            const int rb = g * 64 + c * 8;
            uint ow[4];
            #pragma unroll
            for (int p = 0; p < 4; ++p) {
                const ushort u0 = f2h(x[(size_t)(rb + 2 * p) * BATCH_ + b0 + n]);
                const ushort u1 = f2h(x[(size_t)(rb + 2 * p + 1) * BATCH_ + b0 + n]);
                ow[p] = (uint)u0 | ((uint)u1 << 16);
            }
            __builtin_memcpy(&xt[n * 128 + (rb ^ swn)], ow, 16);
        }
    }
    __syncthreads();

    f32x4 acc[4][4];
    #pragma unroll
    for (int mt = 0; mt < 4; ++mt)
        #pragma unroll
        for (int nt = 0; nt < 4; ++nt)
            acc[mt][nt] = (f32x4){0.f, 0.f, 0.f, 0.f};

    const ushort* xbase = xt + (wn * 64 + l16) * 128;

    // ================= identity steps (kt = 0,1; sp==0 only) =================
    if (sp == 0) {
        for (int kt = 0; kt < 2; ++kt) {
            half8 af[8];
            load_af(af, wt, kt, wm, lane);
            #pragma unroll
            for (int kk = 0; kk < 2; ++kk) {
                const int off = (kt * 64 + kk * 32 + quad * 8) ^ sw;
                #pragma unroll
                for (int nt = 0; nt < 4; ++nt) {
                    const half8 bfr = *(const half8*)(xbase + nt * 2048 + off);
                    #pragma unroll
                    for (int mt = 0; mt < 4; ++mt)
                        acc[mt][nt] = __builtin_amdgcn_mfma_f32_16x16x32_f16(
                            af[kk * 4 + mt], bfr, acc[mt][nt], 0, 0, 0);
                }
            }
        }
    }

    // ================= NICE steps, software-pipelined =================
    {
        const int s_ni = (kt0 > 2) ? kt0 : 2;
        const int e_ni = (kt1 < 124) ? kt1 : 124;
        int kt = s_ni;
        if (kt < e_ni) {
            half8 afA[8], afB[8];
            load_af(afA, wt, kt, wm, lane);
            uint w0 = *(const uint*)(pp + kt * 64 + quad * 8);
            uint w1 = *(const uint*)(pp + kt * 64 + 32 + quad * 8);
            while (true) {
                {   // consume afA, prefetch afB
                    const int ktn = (kt + 1 < e_ni) ? kt + 1 : kt;
                    load_af(afB, wt, ktn, wm, lane);
                    const uint nw0 = *(const uint*)(pp + ktn * 64 + quad * 8);
                    const uint nw1 = *(const uint*)(pp + ktn * 64 + 32 + quad * 8);
                    step_nice(acc, afA, w0, w1, xbase, sw);
                    w0 = nw0; w1 = nw1; ++kt;
                }
                if (kt >= e_ni) break;
                {   // consume afB, prefetch afA
                    const int ktn = (kt + 1 < e_ni) ? kt + 1 : kt;
                    load_af(afA, wt, ktn, wm, lane);
                    const uint nw0 = *(const uint*)(pp + ktn * 64 + quad * 8);
                    const uint nw1 = *(const uint*)(pp + ktn * 64 + 32 + quad * 8);
                    step_nice(acc, afB, w0, w1, xbase, sw);
                    w0 = nw0; w1 = nw1; ++kt;
                }
                if (kt >= e_ni) break;
            }
        }
    }

    // ================= ragged steps (kt = 124..130; sp==3 only) =================
    if (sp == 3) {
        for (int kt = 124; kt < NKT; ++kt) {
            half8 af[8];
            load_af(af, wt, kt, wm, lane);
            #pragma unroll
            for (int kk = 0; kk < 2; ++kk) {
                const int k0 = kt * 64 + kk * 32 + quad * 8;
                const uint4 pk = *(const uint4*)(pp + k0);
                const uint pr4[4] = {pk.x, pk.y, pk.z, pk.w};
                #pragma unroll
                for (int nt = 0; nt < 4; ++nt) {
                    const ushort* xb = xbase + nt * 2048;
                    float prods[8];
                    #pragma unroll
                    for (int e = 0; e < 8; ++e) {
                        const uint ent = (pr4[e >> 1] >> ((e & 1) * 16)) & 0xFFFFu;
                        prods[e] = h2f(xb[(int)(ent & 0xFFu) ^ sw]) *
                                   h2f(xb[(int)(ent >> 8) ^ sw]);
                    }
                    union { half8 h; uint wdw[4]; } bb;
                    #pragma unroll
                    for (int p = 0; p < 4; ++p) {
                        const auto pk2 = __builtin_amdgcn_cvt_pkrtz(
                            prods[2 * p], prods[2 * p + 1]);
                        __builtin_memcpy(&bb.wdw[p], &pk2, 4);
                    }
                    const half8 bfr = bb.h;
                    #pragma unroll
                    for (int mt = 0; mt < 4; ++mt)
                        acc[mt][nt] = __builtin_amdgcn_mfma_f32_16x16x32_f16(
                            af[kk * 4 + mt], bfr, acc[mt][nt], 0, 0, 0);
                }
            }
        }
    }

    // ---- epilogue: atomic accumulate (C/D: col=lane&15, row=quad*4+reg) ----
    #pragma unroll
    for (int mt = 0; mt < 4; ++mt) {
        #pragma unroll
        for (int nt = 0; nt < 4; ++nt) {
            const int mbase = wm * 64 + mt * 16 + quad * 4;
            const size_t col = (size_t)b0 + wn * 64 + nt * 16 + l16;
            #pragma unroll
            for (int r = 0; r < 4; ++r)
                unsafeAtomicAdd(&out[(size_t)(mbase + r) * BATCH_ + col],
                                acc[mt][nt][r]);
        }
    }
}

extern "C" void kernel_launch(void* const* d_in, const int* in_sizes, int n_in,
                              void* d_out, int out_size, void* d_ws, size_t ws_size,
                              hipStream_t stream) {
    const float* x = (const float*)d_in[0];   // [128, 16384]
    const float* A = (const float*)d_in[1];   // [128, 128]
    const float* B = (const float*)d_in[2];   // [128, 8256]
    float* out = (float*)d_out;               // [128, 16384]

    ushort* wt = (ushort*)d_ws;
    ushort* pp = (ushort*)((char*)d_ws + PP_OFF);

    build_all<<<781, 256, 0, stream>>>(A, B, pp, wt, out);
    gemm_mfma<<<dim3(BATCH_ / 256, 4), 512, 0, stream>>>(x, wt, pp, out);
}

// Round 5
// 119.608 us; speedup vs baseline: 1.0734x; 1.0734x over previous
//
#include <hip/hip_runtime.h>

// out[128,16384] = [A|B](128x8384) @ [x; x2](8384x16384), fp16 MFMA.
// Round 14 = round 13 + chain-starvation fix.
// Evidence trail: r10 (waves x2) null, r12 (VALU /2) -5%, r13 (wt bytes /2)
// null => the invariant is MFMA/CU = 8448 at 18.7 cyc each vs 4.85 capacity:
// pipe starves during each wave's serial LDS->VALU->pack chain, and all 8
// waves run IN PHASE so bursts collide. Fixes:
//   1. depth-2 pipeline: iteration issues pp-words for kt+2 + LDS reads for
//      kt+1, computes kt from inputs loaded a full iteration ago -> LDS/L2
//      latency off the critical path.
//   2. per-wave K-rotation (commutative sum): wave w starts at kt0+w*len/8,
//      wraps -> MFMA bursts of different waves interleave.
//   3. s_setprio(1) around MFMA cluster (pays only with de-phased waves).
// DO NOT add __launch_bounds__ min-waves: clamped VGPR -> spills (r6).
// K permutation: identity k'<128 (steps 0-1) | NICE [128,7936) (steps 2-123,
// uniform i, aligned j-octet) | RAGGED [7936,8384) (steps 124-130, gather).

constexpr int N_     = 128;
constexpr int S_     = 8256;
constexpr int BATCH_ = 16384;
constexpr int KTOT   = 8384;         // 131*64
constexpr int NKT    = 131;
constexpr size_t WT_BYTES = (size_t)KTOT * 128 * 2;
constexpr size_t PP_OFF   = WT_BYTES;

typedef __attribute__((ext_vector_type(8))) _Float16 half8;
typedef __attribute__((ext_vector_type(2))) _Float16 half2t;
typedef __attribute__((ext_vector_type(4))) float f32x4;

__device__ __forceinline__ ushort f2h(float f) {     // f32 -> fp16 bits (RNE)
    _Float16 h = (_Float16)f;
    ushort b; __builtin_memcpy(&b, &h, 2); return b;
}
__device__ __forceinline__ float h2f(ushort b) {
    _Float16 h; __builtin_memcpy(&h, &b, 2); return (float)h;
}
__device__ __forceinline__ half2t duph(ushort b) {   // {h, h} packed
    uint w = ((uint)b << 16) | (uint)b;
    half2t d; __builtin_memcpy(&d, &w, 4); return d;
}
__device__ __forceinline__ half8 mul_bc(half8 w, half2t d) {  // 4x v_pk_mul_f16
    union { half8 h; half2t p[4]; } u, r;
    u.h = w;
    #pragma unroll
    for (int q = 0; q < 4; ++q) r.p[q] = u.p[q] * d;
    return r.h;
}

// ---------- closed-form permutation helpers ----------
// cumN(i) = #NICE octets for rows < i = sum_{q<i} (16 - ceil(q/8))
__device__ __forceinline__ int cumN(int i) {
    if (i <= 0) return 0;
    const int n = i - 1, t = n >> 3, r = n & 7;
    return 16 * i - (4 * t * (t + 1) + r * (t + 1));
}
// offR(i) = #ragged entries for rows < i = sum_{q<i} ((8-(q&7))&7)
__device__ __forceinline__ int offR(int i) {
    const int a = i >> 3, b = i & 7;
    const int p = b ? (8 * (b - 1) - (((b - 1) * b) >> 1)) : 0;
    return 28 * a + p;
}
__device__ __forceinline__ int triS(int i) { return i * (257 - i) / 2; }

// ---------- fused build: zero out + pp table + wt (no internal deps) ----------
__global__ __launch_bounds__(256) void build_all(
    const float* __restrict__ A, const float* __restrict__ B,
    ushort* __restrict__ pp, ushort* __restrict__ wt,
    float* __restrict__ out)
{
    const int bid = blockIdx.x, t = threadIdx.x;
    if (bid < 524) {                              // ---- W: 1048 k-octets x 128 m ----
        const int idx = bid * 256 + t;            // [0, 134144)
        const int ko  = idx >> 7;                 // k-octet
        const int m   = idx & 127;
        const int kt = ko >> 3, kk = (ko >> 2) & 1, oct = ko & 3;
        const int lane = oct * 16 + (m & 15);
        const int e0 = kt * 8192 + kk * 4096 + (m >> 6) * 2048 +
                       ((m >> 4) & 3) * 512 + lane * 8;
        float v[8];
        if (ko < 16) {                            // identity: k = ko*8+el, A[m][k]
            const int i0 = ko * 8;
            #pragma unroll
            for (int el = 0; el < 8; ++el) v[el] = A[m * 128 + i0 + el];
        } else if (ko < 992) {                    // NICE: uniform i, aligned j-octet
            const int o = ko - 16;
            int i = 0;
            #pragma unroll
            for (int st = 64; st >= 1; st >>= 1) {
                const int c = i + st;
                if (c < 128 && cumN(c) <= o) i = c;
            }
            const int jb = ((i + 7) >> 3) + (o - cumN(i));
            const int s0 = triS(i) + jb * 8 - i;  // s = tri(i) + (j - i)
            const float* bp = B + (size_t)m * S_ + s0;
            #pragma unroll
            for (int el = 0; el < 8; ++el) v[el] = bp[el];
        } else {                                  // RAGGED: per-el gather
            const int kb = ko * 8 - 7936;
            #pragma unroll
            for (int el = 0; el < 8; ++el) {
                const int kloc = kb + el;
                int i = 0;
                #pragma unroll
                for (int st = 64; st >= 1; st >>= 1) {
                    const int c = i + st;
                    if (c < 128 && offR(c) <= kloc) i = c;
                }
                v[el] = B[(size_t)m * S_ + triS(i) + (kloc - offR(i))];
            }
        }
        ushort o8[8];
        #pragma unroll
        for (int el = 0; el < 8; ++el) o8[el] = f2h(v[el]);
        __builtin_memcpy(wt + e0, o8, 16);
    } else if (bid < 780) {                       // ---- Z: zero out ----
        const int zb = bid - 524;
        f32x4* o4 = (f32x4*)out;
        #pragma unroll
        for (int c = 0; c < 4; ++c)
            o4[(size_t)zb * 2048 + c * 512 + t] = (f32x4){0.f, 0.f, 0.f, 0.f};
    } else {                                      // ---- P: pp table ----
        const int i = t;
        if (i < 128) {
            pp[i] = (ushort)(i | (0xFFu << 8));
            const int jb0 = (i + 7) >> 3;
            int kb = 128 + cumN(i) * 8;
            for (int jb = jb0; jb < 16; ++jb) {
                #pragma unroll
                for (int e = 0; e < 8; ++e)
                    pp[kb + e] = (ushort)(i | ((jb * 8 + e) << 8));
                kb += 8;
            }
            const int h = (8 - (i & 7)) & 7;
            const int rb = 7936 + offR(i);
            for (int e = 0; e < h; ++e)
                pp[rb + e] = (ushort)(i | ((i + e) << 8));
        }
    }
}

// A-frags for step kt: 8 lane-linear b128 loads (coalesced layout).
__device__ __forceinline__ void load_af(half8 af[8], const ushort* __restrict__ wt,
                                        int kt, int wm, int lane) {
    const ushort* ab = wt + ((size_t)kt << 13) + (wm << 11) + (lane << 3);
    #pragma unroll
    for (int kk = 0; kk < 2; ++kk)
        #pragma unroll
        for (int mt = 0; mt < 4; ++mt)
            af[kk * 4 + mt] = *(const half8*)(ab + (kk << 12) + (mt << 9));
}

// Issue the LDS reads for one NICE step (8 scalar + 8 b128, all independent).
__device__ __forceinline__ void read_bin(ushort xi[2][4], half8 wj[2][4],
                                         uint w0, uint w1,
                                         const ushort* __restrict__ xbase,
                                         int sw) {
    const int ia = (int)(w0 & 0xFFu) ^ sw, ja = (int)((w0 >> 8) & 0xFFu) ^ sw;
    const int ib = (int)(w1 & 0xFFu) ^ sw, jb = (int)((w1 >> 8) & 0xFFu) ^ sw;
    #pragma unroll
    for (int nt = 0; nt < 4; ++nt) {
        const ushort* xb = xbase + nt * 2048;
        xi[0][nt] = xb[ia];
        xi[1][nt] = xb[ib];
        wj[0][nt] = *(const half8*)(xb + ja);
        wj[1][nt] = *(const half8*)(xb + jb);
    }
}

// Pack B-frags (inputs loaded a full iteration ago) + 32 MFMA under setprio.
__device__ __forceinline__ void mfma_step(f32x4 acc[4][4], const half8 af[8],
                                          const ushort xi[2][4],
                                          const half8 wj[2][4]) {
    half8 bfr[2][4];
    #pragma unroll
    for (int kk = 0; kk < 2; ++kk)
        #pragma unroll
        for (int nt = 0; nt < 4; ++nt)
            bfr[kk][nt] = mul_bc(wj[kk][nt], duph(xi[kk][nt]));
    __builtin_amdgcn_s_setprio(1);
    #pragma unroll
    for (int kk = 0; kk < 2; ++kk)
        #pragma unroll
        for (int nt = 0; nt < 4; ++nt)
            #pragma unroll
            for (int mt = 0; mt < 4; ++mt)
                acc[mt][nt] = __builtin_amdgcn_mfma_f32_16x16x32_f16(
                    af[kk * 4 + mt], bfr[kk][nt], acc[mt][nt], 0, 0, 0);
    __builtin_amdgcn_s_setprio(0);
}

// ---------- phase 2: fused MFMA GEMM, 128x256 tile, split-K x4 ----------
__global__ __launch_bounds__(512) void gemm_mfma(
    const float*  __restrict__ x,
    const ushort* __restrict__ wt,
    const ushort* __restrict__ pp,
    float* __restrict__ out)
{
    __shared__ ushort xt[256 * 128];   // exactly 64 KB, octet-XOR swizzled

    const int t    = threadIdx.x;
    const int b0   = blockIdx.x * 256;
    const int sp   = blockIdx.y;       // 0..3
    const int kt0  = sp * 33;          // 0,33,66,99
    const int kt1  = (sp == 3) ? NKT : kt0 + 33;
    const int lane = t & 63;
    const int w    = t >> 6;
    const int wm   = w >> 2, wn = w & 3;   // wave covers 64 m x 64 n
    const int l16  = lane & 15, quad = lane >> 4;
    const int sw   = (l16 & 7) << 3;

    // ---- stage xt: coalesced global reads, fp16, swizzled b128 LDS writes ----
    {
        const int n = t & 255, g = t >> 8;
        const int swn = (n & 7) << 3;
        #pragma unroll
        for (int c = 0; c < 8; ++c) {
            const int rb = g * 64 + c * 8;
            uint ow[4];
            #pragma unroll
            for (int p = 0; p < 4; ++p) {
                const ushort u0 = f2h(x[(size_t)(rb + 2 * p) * BATCH_ + b0 + n]);
                const ushort u1 = f2h(x[(size_t)(rb + 2 * p + 1) * BATCH_ + b0 + n]);
                ow[p] = (uint)u0 | ((uint)u1 << 16);
            }
            __builtin_memcpy(&xt[n * 128 + (rb ^ swn)], ow, 16);
        }
    }
    __syncthreads();

    f32x4 acc[4][4];
    #pragma unroll
    for (int mt = 0; mt < 4; ++mt)
        #pragma unroll
        for (int nt = 0; nt < 4; ++nt)
            acc[mt][nt] = (f32x4){0.f, 0.f, 0.f, 0.f};

    const ushort* xbase = xt + (wn * 64 + l16) * 128;

    // ================= identity steps (kt = 0,1; sp==0 only) =================
    if (sp == 0) {
        for (int kt = 0; kt < 2; ++kt) {
            half8 af[8];
            load_af(af, wt, kt, wm, lane);
            #pragma unroll
            for (int kk = 0; kk < 2; ++kk) {
                const int off = (kt * 64 + kk * 32 + quad * 8) ^ sw;
                #pragma unroll
                for (int nt = 0; nt < 4; ++nt) {
                    const half8 bfr = *(const half8*)(xbase + nt * 2048 + off);
                    #pragma unroll
                    for (int mt = 0; mt < 4; ++mt)
                        acc[mt][nt] = __builtin_amdgcn_mfma_f32_16x16x32_f16(
                            af[kk * 4 + mt], bfr, acc[mt][nt], 0, 0, 0);
                }
            }
        }
    }

    // ====== NICE steps: depth-2 pipeline, per-wave rotation, setprio ======
    {
        const int s_ni = (kt0 > 2) ? kt0 : 2;
        const int e_ni = (kt1 < 124) ? kt1 : 124;
        const int len  = e_ni - s_ni;
        if (len > 0) {
            // rotated start: de-phase the 8 waves (sum is commutative)
            int kt  = s_ni + ((w * len) >> 3);
            int ktn = (kt + 1 < e_ni) ? kt + 1 : s_ni;

            half8  afA[8], afB[8];
            ushort xiA[2][4], xiB[2][4];
            half8  wjA[2][4], wjB[2][4];

            // prologue: words+bin+af for kt; words for kt+1
            const uint c0 = *(const uint*)(pp + kt * 64 + quad * 8);
            const uint c1 = *(const uint*)(pp + kt * 64 + 32 + quad * 8);
            load_af(afA, wt, kt, wm, lane);
            uint n0 = *(const uint*)(pp + ktn * 64 + quad * 8);
            uint n1 = *(const uint*)(pp + ktn * 64 + 32 + quad * 8);
            read_bin(xiA, wjA, c0, c1, xbase, sw);

            int rem = len;
            while (true) {
                {   // compute kt from A-buffers; prefetch ktn into B-buffers
                    const int kt2 = (ktn + 1 < e_ni) ? ktn + 1 : s_ni;
                    const uint m0 = *(const uint*)(pp + kt2 * 64 + quad * 8);
                    const uint m1 = *(const uint*)(pp + kt2 * 64 + 32 + quad * 8);
                    load_af(afB, wt, ktn, wm, lane);
                    read_bin(xiB, wjB, n0, n1, xbase, sw);
                    mfma_step(acc, afA, xiA, wjA);
                    n0 = m0; n1 = m1; ktn = kt2;
                    if (--rem == 0) break;
                }
                {   // swap roles
                    const int kt2 = (ktn + 1 < e_ni) ? ktn + 1 : s_ni;
                    const uint m0 = *(const uint*)(pp + kt2 * 64 + quad * 8);
                    const uint m1 = *(const uint*)(pp + kt2 * 64 + 32 + quad * 8);
                    load_af(afA, wt, ktn, wm, lane);
                    read_bin(xiA, wjA, n0, n1, xbase, sw);
                    mfma_step(acc, afB, xiB, wjB);
                    n0 = m0; n1 = m1; ktn = kt2;
                    if (--rem == 0) break;
                }
            }
        }
    }

    // ================= ragged steps (kt = 124..130; sp==3 only) =================
    if (sp == 3) {
        for (int kt = 124; kt < NKT; ++kt) {
            half8 af[8];
            load_af(af, wt, kt, wm, lane);
            #pragma unroll
            for (int kk = 0; kk < 2; ++kk) {
                const int k0 = kt * 64 + kk * 32 + quad * 8;
                const uint4 pk = *(const uint4*)(pp + k0);
                const uint pr4[4] = {pk.x, pk.y, pk.z, pk.w};
                #pragma unroll
                for (int nt = 0; nt < 4; ++nt) {
                    const ushort* xb = xbase + nt * 2048;
                    float prods[8];
                    #pragma unroll
                    for (int e = 0; e < 8; ++e) {
                        const uint ent = (pr4[e >> 1] >> ((e & 1) * 16)) & 0xFFFFu;
                        prods[e] = h2f(xb[(int)(ent & 0xFFu) ^ sw]) *
                                   h2f(xb[(int)(ent >> 8) ^ sw]);
                    }
                    union { half8 h; uint wdw[4]; } bb;
                    #pragma unroll
                    for (int p = 0; p < 4; ++p) {
                        const auto pk2 = __builtin_amdgcn_cvt_pkrtz(
                            prods[2 * p], prods[2 * p + 1]);
                        __builtin_memcpy(&bb.wdw[p], &pk2, 4);
                    }
                    const half8 bfr = bb.h;
                    #pragma unroll
                    for (int mt = 0; mt < 4; ++mt)
                        acc[mt][nt] = __builtin_amdgcn_mfma_f32_16x16x32_f16(
                            af[kk * 4 + mt], bfr, acc[mt][nt], 0, 0, 0);
                }
            }
        }
    }

    // ---- epilogue: atomic accumulate (C/D: col=lane&15, row=quad*4+reg) ----
    #pragma unroll
    for (int mt = 0; mt < 4; ++mt) {
        #pragma unroll
        for (int nt = 0; nt < 4; ++nt) {
            const int mbase = wm * 64 + mt * 16 + quad * 4;
            const size_t col = (size_t)b0 + wn * 64 + nt * 16 + l16;
            #pragma unroll
            for (int r = 0; r < 4; ++r)
                unsafeAtomicAdd(&out[(size_t)(mbase + r) * BATCH_ + col],
                                acc[mt][nt][r]);
        }
    }
}

extern "C" void kernel_launch(void* const* d_in, const int* in_sizes, int n_in,
                              void* d_out, int out_size, void* d_ws, size_t ws_size,
                              hipStream_t stream) {
    const float* x = (const float*)d_in[0];   // [128, 16384]
    const float* A = (const float*)d_in[1];   // [128, 128]
    const float* B = (const float*)d_in[2];   // [128, 8256]
    float* out = (float*)d_out;               // [128, 16384]

    ushort* wt = (ushort*)d_ws;
    ushort* pp = (ushort*)((char*)d_ws + PP_OFF);

    build_all<<<781, 256, 0, stream>>>(A, B, pp, wt, out);
    gemm_mfma<<<dim3(BATCH_ / 256, 4), 512, 0, stream>>>(x, wt, pp, out);
}